// Round 7
// baseline (142.571 us; speedup 1.0000x reference)
//
#include <hip/hip_runtime.h>
#include <math.h>

// Problem constants
#define H_GRID 32
#define W_GRID 64
#define NTOK   2048
#define NHEADS 8
#define HD     24
#define DIMC   192
#define BATCH  4

static constexpr float SCALE = 0.20412414523193154f; // 1/sqrt(24)

typedef unsigned short ushort;
typedef unsigned int   uint;
typedef __attribute__((ext_vector_type(8))) short bf16x8;
typedef __attribute__((ext_vector_type(4))) float f32x4;

static __device__ __forceinline__ float4 ld4(const float* p) { return *(const float4*)p; }

static __device__ __forceinline__ ushort f2bf(float f) {   // RNE to bf16
    union { float f; uint u; } c; c.f = f;
    uint u = c.u;
    uint r = u + 0x7fffu + ((u >> 16) & 1u);
    return (ushort)(r >> 16);
}
static __device__ __forceinline__ float bf2f(ushort h) {
    union { uint u; float f; } c; c.u = ((uint)h) << 16; return c.f;
}

// ---------------------------------------------------------------------------
// cast_split: split x (8192x192), qkv_w (576x192), proj_w (192x192) into bf16
// hi/lo pairs, and zero-fill the d-pad (24..31) of Qhi/Qlo/Khi/Klo.
// Thread ranges (one float4 chunk or one 16B zero store each):
//   [0,393216)        x chunks
//   [393216,420864)   wq chunks
//   [420864,430080)   wp chunks
//   [430080,692224)   zero-fill: 4 tensors x 65536 rows, 8 ushorts @ d=24
// ---------------------------------------------------------------------------
__global__ __launch_bounds__(256) void cast_split(const float* __restrict__ x,
                                                  const float* __restrict__ wq,
                                                  const float* __restrict__ wp,
                                                  ushort* __restrict__ xhi, ushort* __restrict__ xlo,
                                                  ushort* __restrict__ wqhi, ushort* __restrict__ wqlo,
                                                  ushort* __restrict__ wphi, ushort* __restrict__ wplo,
                                                  ushort* __restrict__ Qhi, ushort* __restrict__ Qlo,
                                                  ushort* __restrict__ Khi, ushort* __restrict__ Klo) {
    const int i = blockIdx.x * 256 + threadIdx.x;
    if (i >= 430080) {                       // zero-fill pads
        const int ti = i - 430080;           // 0..262143
        const int tensor = ti >> 16;         // 0..3
        const int row = ti & 65535;          // 0..65535 (b*8+h)*2048+tok
        ushort* dst = (tensor == 0) ? Qhi : (tensor == 1) ? Qlo
                    : (tensor == 2) ? Khi : Klo;
        const uint4 z = {0u, 0u, 0u, 0u};
        *(uint4*)&dst[(size_t)row * 32 + 24] = z;
        return;
    }
    const float* src; ushort *dh, *dl; int off;
    if (i < 393216)      { src = x;  dh = xhi;  dl = xlo;  off = i; }
    else if (i < 420864) { src = wq; dh = wqhi; dl = wqlo; off = i - 393216; }
    else                 { src = wp; dh = wphi; dl = wplo; off = i - 420864; }
    float4 v = ld4(src + (size_t)off * 4);
    float a[4] = {v.x, v.y, v.z, v.w};
    ushort h[4], l[4];
#pragma unroll
    for (int j = 0; j < 4; j++) {
        h[j] = f2bf(a[j]);
        l[j] = f2bf(a[j] - bf2f(h[j]));
    }
    *(ushort4*)(dh + (size_t)off * 4) = make_ushort4(h[0], h[1], h[2], h[3]);
    *(ushort4*)(dl + (size_t)off * 4) = make_ushort4(l[0], l[1], l[2], l[3]);
}

// ---------------------------------------------------------------------------
// QKV GEMM (split-bf16 MFMA): computes x @ W^T + b and writes directly into
// attention-ready layouts:
//   Q (band 0): Qhi/Qlo [b,h,tok,32] (d-pad zeros via cast_split), scaled
//   K (band 1): Khi/Klo same layout
//   V (band 2): VThi/VTlo [b,h,d(32 rows, 24 used),2048]  (transposed!)
// A (x) pre-split bf16, per-lane 16B fragment loads from global.
// W band in LDS, rows padded to 200 us (2-way conflicts = free).
// blockIdx.y selects the 64-col band; bands 0-2=Q, 3-5=K, 6-8=V.
// ---------------------------------------------------------------------------
__global__ __launch_bounds__(256) void gemm_qkv(const ushort* __restrict__ Ahi,
                                                const ushort* __restrict__ Alo,
                                                const ushort* __restrict__ Wh,
                                                const ushort* __restrict__ Wl,
                                                const float* __restrict__ bias,
                                                ushort* __restrict__ Qhi, ushort* __restrict__ Qlo,
                                                ushort* __restrict__ Khi, ushort* __restrict__ Klo,
                                                ushort* __restrict__ VThi, ushort* __restrict__ VTlo) {
    __shared__ ushort Wsh[64 * 200];
    __shared__ ushort Wsl[64 * 200];

    const int t    = threadIdx.x;
    const int wave = t >> 6, lane = t & 63;
    const int m0   = blockIdx.x * 64 + wave * 16;
    const int j0   = blockIdx.y * 64;
    const int row  = lane & 15;
    const int kq   = lane >> 4;

    for (int i = t; i < 1536; i += 256) {
        const int r = i / 24, c = i - (i / 24) * 24;
        *(uint4*)&Wsh[r * 200 + c * 8] = *(const uint4*)&Wh[(size_t)(j0 + r) * 192 + c * 8];
        *(uint4*)&Wsl[r * 200 + c * 8] = *(const uint4*)&Wl[(size_t)(j0 + r) * 192 + c * 8];
    }

    const ushort* ah = Ahi + (size_t)(m0 + row) * 192 + kq * 8;
    const ushort* al = Alo + (size_t)(m0 + row) * 192 + kq * 8;

    f32x4 acc[4] = {f32x4{0,0,0,0}, f32x4{0,0,0,0}, f32x4{0,0,0,0}, f32x4{0,0,0,0}};

    __syncthreads();

#pragma unroll
    for (int ks = 0; ks < 6; ks++) {
        bf16x8 afh = *(const bf16x8*)(ah + ks * 32);
        bf16x8 afl = *(const bf16x8*)(al + ks * 32);
#pragma unroll
        for (int nt = 0; nt < 4; nt++) {
            const int widx = (nt * 16 + row) * 200 + kq * 8 + ks * 32;
            bf16x8 bh = *(const bf16x8*)&Wsh[widx];
            bf16x8 bl = *(const bf16x8*)&Wsl[widx];
            acc[nt] = __builtin_amdgcn_mfma_f32_16x16x32_bf16(afh, bh, acc[nt], 0, 0, 0);
            acc[nt] = __builtin_amdgcn_mfma_f32_16x16x32_bf16(afl, bh, acc[nt], 0, 0, 0);
            acc[nt] = __builtin_amdgcn_mfma_f32_16x16x32_bf16(afh, bl, acc[nt], 0, 0, 0);
        }
    }

    // epilogue: C row m = m0 + kq*4 + r, col = j0 + nt*16 + row
    const int band = blockIdx.y / 3;          // 0=Q, 1=K, 2=V
    const int tok0 = (m0 + kq * 4) & 2047;
    const int b_   = (m0 + kq * 4) >> 11;
#pragma unroll
    for (int nt = 0; nt < 4; nt++) {
        const int col = j0 + nt * 16 + row;
        const int lc  = col - band * 192;     // 0..191
        const int h_  = lc / 24;
        const int d_  = lc - h_ * 24;
        const float bv = bias[col];
        if (band == 2) {                      // V -> transposed VT[b,h,d,2048]
            ushort vh[4], vl[4];
#pragma unroll
            for (int r = 0; r < 4; r++) {
                const float val = acc[nt][r] + bv;
                vh[r] = f2bf(val);
                vl[r] = f2bf(val - bf2f(vh[r]));
            }
            const size_t addr = ((size_t)(b_ * 8 + h_) * 32 + d_) * 2048 + tok0;
            *(ushort4*)&VThi[addr] = make_ushort4(vh[0], vh[1], vh[2], vh[3]);
            *(ushort4*)&VTlo[addr] = make_ushort4(vl[0], vl[1], vl[2], vl[3]);
        } else {
            ushort* dh = band ? Khi : Qhi;
            ushort* dl = band ? Klo : Qlo;
            const float sc_ = band ? 1.0f : SCALE;
#pragma unroll
            for (int r = 0; r < 4; r++) {
                const float val = (acc[nt][r] + bv) * sc_;
                const ushort hh = f2bf(val);
                const size_t addr = ((size_t)(b_ * 8 + h_) * 2048 + tok0 + r) * 32 + d_;
                dh[addr] = hh;
                dl[addr] = f2bf(val - bf2f(hh));
            }
        }
    }
}

// ---------------------------------------------------------------------------
// MFMA local attention, staging-free inputs.
// Window per 4x8 query tile: rows kh = qh0-3..qh0+6 (10), cols [kw0a, kw0a+32)
// with kw0a = max(qw0-8,0) -> 320 padded slots; slot = rr*32 + cc.
// QK^T: Q/K fragments DIRECT from global (pre-split, d-padded); 20 n-tiles.
// Softmax in registers (shuffle over 16 lanes + partner-wave LDS exchange).
// P: bf16 (hi only) in LDS [32][328]; normalization by sum of ROUNDED p.
// PV: P A-frags from LDS; V^T B-frags DIRECT from global ([b,h,d,2048]).
// Out-of-window addresses clamped in-bounds (finite) and geometry-masked.
// LDS ~21.5 KB, 2 barriers.
// ---------------------------------------------------------------------------
__global__ __launch_bounds__(256) void attn_mfma(const ushort* __restrict__ Qhi,
                                                 const ushort* __restrict__ Qlo,
                                                 const ushort* __restrict__ Khi,
                                                 const ushort* __restrict__ Klo,
                                                 const ushort* __restrict__ VThi,
                                                 const ushort* __restrict__ VTlo,
                                                 ushort* __restrict__ ahi,
                                                 ushort* __restrict__ alo) {
    const int qtile = blockIdx.x;
    const int head  = blockIdx.y;
    const int b     = blockIdx.z;
    const int qh0   = (qtile >> 3) * 4;
    const int qw0   = (qtile & 7) * 8;
    const int kw0a  = max(qw0 - 8, 0);       // aligned 32-col window start

    const int t = threadIdx.x;
    const int w = t >> 6, lane = t & 63;
    const int n16 = lane & 15, quad = lane >> 4;
    const int bh = b * 8 + head;

    __shared__ ushort Phi[32 * 328];
    __shared__ float  mxbuf[64];
    __shared__ float  sumbuf[64];

    const ushort* Qh_b = Qhi + (size_t)bh * 2048 * 32;
    const ushort* Ql_b = Qlo + (size_t)bh * 2048 * 32;
    const ushort* Kh_b = Khi + (size_t)bh * 2048 * 32;
    const ushort* Kl_b = Klo + (size_t)bh * 2048 * 32;
    const ushort* Vh_b = VThi + (size_t)bh * 32 * 2048;
    const ushort* Vl_b = VTlo + (size_t)bh * 32 * 2048;

    const int mt = w >> 1, nth = w & 1;

    // ---- Q A-fragment (direct global, d-padded zeros at quad=3) ----
    const int mrow = 16 * mt + n16;
    const int tq_a = ((qh0 + (mrow >> 3)) << 6) + qw0 + (mrow & 7);
    const bf16x8 qfh = *(const bf16x8*)&Qh_b[(size_t)tq_a * 32 + quad * 8];
    const bf16x8 qfl = *(const bf16x8*)&Ql_b[(size_t)tq_a * 32 + quad * 8];

    // ---- QK^T over this wave's 10 n-tiles; mask+max inline ----
    const int m0r = quad * 4;
    float sv[10][4];
    float mx4[4] = {-3e38f, -3e38f, -3e38f, -3e38f};
#pragma unroll
    for (int j = 0; j < 10; j++) {
        const int slot = (nth * 10 + j) * 16 + n16;
        const int rr = slot >> 5, cc = slot & 31;
        const int khv = qh0 - 3 + rr;
        const int kwv = kw0a + cc;
        const int kh_cl = min(max(khv, 0), 31);
        const int tok   = (kh_cl << 6) + min(kwv, 63);
        const bf16x8 kfh = *(const bf16x8*)&Kh_b[(size_t)tok * 32 + quad * 8];
        const bf16x8 kfl = *(const bf16x8*)&Kl_b[(size_t)tok * 32 + quad * 8];
        f32x4 a = f32x4{0, 0, 0, 0};
        a = __builtin_amdgcn_mfma_f32_16x16x32_bf16(qfh, kfh, a, 0, 0, 0);
        a = __builtin_amdgcn_mfma_f32_16x16x32_bf16(qfl, kfh, a, 0, 0, 0);
        a = __builtin_amdgcn_mfma_f32_16x16x32_bf16(qfh, kfl, a, 0, 0, 0);
        const bool khok = (khv >= 0) && (khv < 32) && (kwv < 64);
#pragma unroll
        for (int r = 0; r < 4; r++) {
            const int m   = 16 * mt + m0r + r;
            const int qhv = qh0 + (m >> 3);
            const int qwv = qw0 + (m & 7);
            const bool valid = khok && (abs(khv - qhv) <= 3) && (abs(kwv - qwv) <= 5);
            const float s = valid ? a[r] : -3e38f;
            sv[j][r] = s;
            mx4[r] = fmaxf(mx4[r], s);
        }
    }
#pragma unroll
    for (int d = 1; d < 16; d <<= 1)
#pragma unroll
        for (int r = 0; r < 4; r++) mx4[r] = fmaxf(mx4[r], __shfl_xor(mx4[r], d));
    if (n16 == 0) {
#pragma unroll
        for (int r = 0; r < 4; r++) mxbuf[w * 16 + m0r + r] = mx4[r];
    }
    __syncthreads();
#pragma unroll
    for (int r = 0; r < 4; r++) mx4[r] = fmaxf(mx4[r], mxbuf[(w ^ 1) * 16 + m0r + r]);

    // ---- exp -> P (bf16 hi only), sums of ROUNDED p ----
    float sum4[4] = {0.f, 0.f, 0.f, 0.f};
#pragma unroll
    for (int j = 0; j < 10; j++) {
        const int col = (nth * 10 + j) * 16 + n16;
#pragma unroll
        for (int r = 0; r < 4; r++) {
            const float p = __expf(sv[j][r] - mx4[r]);
            const ushort ph = f2bf(p);
            sum4[r] += bf2f(ph);
            Phi[(16 * mt + m0r + r) * 328 + col] = ph;
        }
    }
#pragma unroll
    for (int d = 1; d < 16; d <<= 1)
#pragma unroll
        for (int r = 0; r < 4; r++) sum4[r] += __shfl_xor(sum4[r], d);
    if (n16 == 0) {
#pragma unroll
        for (int r = 0; r < 4; r++) sumbuf[w * 16 + m0r + r] = sum4[r];
    }
    __syncthreads();

    // ---- PV: 10 ksteps of 32 slots; V^T B-frags direct from global ----
    const int mtP = w >> 1, ntP = w & 1;
    const int dr  = 16 * ntP + n16;            // output dim (rows >=24 discarded)
    f32x4 accA = f32x4{0,0,0,0}, accB = f32x4{0,0,0,0};
#pragma unroll
    for (int ks = 0; ks < 10; ks++) {
        const int khv   = qh0 - 3 + ks;
        const int kh_cl = min(max(khv, 0), 31);
        const int seg   = min((kh_cl << 6) + kw0a + quad * 8, 2040);
        const bf16x8 pa = *(const bf16x8*)&Phi[(16 * mtP + n16) * 328 + ks * 32 + quad * 8];
        const bf16x8 vh = *(const bf16x8*)&Vh_b[(size_t)dr * 2048 + seg];
        const bf16x8 vl = *(const bf16x8*)&Vl_b[(size_t)dr * 2048 + seg];
        accA = __builtin_amdgcn_mfma_f32_16x16x32_bf16(pa, vh, accA, 0, 0, 0);
        accB = __builtin_amdgcn_mfma_f32_16x16x32_bf16(pa, vl, accB, 0, 0, 0);
    }

    // ---- epilogue: normalize, emit bf16 hi/lo for proj ----
    if (dr < 24) {
#pragma unroll
        for (int r = 0; r < 4; r++) {
            const int m = 16 * mtP + quad * 4 + r;
            const float tot = sumbuf[(2 * mtP) * 16 + (m & 15)] +
                              sumbuf[(2 * mtP + 1) * 16 + (m & 15)];
            const float val = (accA[r] + accB[r]) / tot;
            const int tq = ((qh0 + (m >> 3)) << 6) + qw0 + (m & 7);
            const size_t ob = (size_t)(b * 2048 + tq) * 192 + head * 24 + dr;
            const ushort hh = f2bf(val);
            ahi[ob] = hh;
            alo[ob] = f2bf(val - bf2f(hh));
        }
    }
}

// ---------------------------------------------------------------------------
// Proj GEMM: out[8192 x 192] = aws[8192 x 192] * W[192 x 192]^T + bias
// A pre-split bf16 (attn epilogue). 128-thread blocks, 32 rows -> 768 blocks.
// ---------------------------------------------------------------------------
__global__ __launch_bounds__(128) void gemm_proj(const ushort* __restrict__ Ahi,
                                                 const ushort* __restrict__ Alo,
                                                 const ushort* __restrict__ Wh,
                                                 const ushort* __restrict__ Wl,
                                                 const float* __restrict__ bias,
                                                 float* __restrict__ C) {
    __shared__ ushort Wsh[64 * 200];
    __shared__ ushort Wsl[64 * 200];

    const int t    = threadIdx.x;
    const int wave = t >> 6, lane = t & 63;
    const int m0   = blockIdx.x * 32 + wave * 16;
    const int j0   = blockIdx.y * 64;
    const int row  = lane & 15;
    const int kq   = lane >> 4;

    for (int i = t; i < 1536; i += 128) {
        const int r = i / 24, c = i - (i / 24) * 24;
        *(uint4*)&Wsh[r * 200 + c * 8] = *(const uint4*)&Wh[(size_t)(j0 + r) * 192 + c * 8];
        *(uint4*)&Wsl[r * 200 + c * 8] = *(const uint4*)&Wl[(size_t)(j0 + r) * 192 + c * 8];
    }

    const ushort* ah = Ahi + (size_t)(m0 + row) * 192 + kq * 8;
    const ushort* al = Alo + (size_t)(m0 + row) * 192 + kq * 8;

    f32x4 acc[4] = {f32x4{0,0,0,0}, f32x4{0,0,0,0}, f32x4{0,0,0,0}, f32x4{0,0,0,0}};

    __syncthreads();

#pragma unroll
    for (int ks = 0; ks < 6; ks++) {
        bf16x8 afh = *(const bf16x8*)(ah + ks * 32);
        bf16x8 afl = *(const bf16x8*)(al + ks * 32);
#pragma unroll
        for (int nt = 0; nt < 4; nt++) {
            const int widx = (nt * 16 + row) * 200 + kq * 8 + ks * 32;
            bf16x8 bh = *(const bf16x8*)&Wsh[widx];
            bf16x8 bl = *(const bf16x8*)&Wsl[widx];
            acc[nt] = __builtin_amdgcn_mfma_f32_16x16x32_bf16(afh, bh, acc[nt], 0, 0, 0);
            acc[nt] = __builtin_amdgcn_mfma_f32_16x16x32_bf16(afl, bh, acc[nt], 0, 0, 0);
            acc[nt] = __builtin_amdgcn_mfma_f32_16x16x32_bf16(afh, bl, acc[nt], 0, 0, 0);
        }
    }

#pragma unroll
    for (int nt = 0; nt < 4; nt++) {
        const int col = j0 + nt * 16 + row;
        const float bv = bias[col];
#pragma unroll
        for (int r = 0; r < 4; r++) {
            const int m = m0 + kq * 4 + r;
            C[(size_t)m * 192 + col] = acc[nt][r] + bv;
        }
    }
}

// ---------------------------------------------------------------------------
// Launch: cast_split -> gemm_qkv (writes attn-ready layouts) -> attn -> proj
// ---------------------------------------------------------------------------
extern "C" void kernel_launch(void* const* d_in, const int* in_sizes, int n_in,
                              void* d_out, int out_size, void* d_ws, size_t ws_size,
                              hipStream_t stream) {
    const float* x      = (const float*)d_in[0];
    const float* qkv_w  = (const float*)d_in[1];
    const float* qkv_b  = (const float*)d_in[2];
    const float* proj_w = (const float*)d_in[3];
    const float* proj_b = (const float*)d_in[4];
    // d_in[5] mask: fixed 7x11 window, recomputed analytically; unused.

    char* wsb = (char*)d_ws;
    ushort* xhi   = (ushort*)(wsb + 0);          // [8192,192]  3,145,728 B
    ushort* xlo   = (ushort*)(wsb + 3145728);
    ushort* wqhi  = (ushort*)(wsb + 6291456);    // [576,192]   221,184 B
    ushort* wqlo  = (ushort*)(wsb + 6512640);
    ushort* wphi  = (ushort*)(wsb + 6733824);    // [192,192]   73,728 B
    ushort* wplo  = (ushort*)(wsb + 6807552);
    ushort* awshi = (ushort*)(wsb + 6881280);    // [8192,192]  3,145,728 B
    ushort* awslo = (ushort*)(wsb + 10027008);
    ushort* Qhi   = (ushort*)(wsb + 13172736);   // [32,2048,32] 4,194,304 B
    ushort* Qlo   = (ushort*)(wsb + 17367040);
    ushort* Khi   = (ushort*)(wsb + 21561344);
    ushort* Klo   = (ushort*)(wsb + 25755648);
    ushort* VThi  = (ushort*)(wsb + 29949952);   // [32,32,2048]
    ushort* VTlo  = (ushort*)(wsb + 34144256);
    float*  out   = (float*)d_out;

    hipLaunchKernelGGL(cast_split, dim3(2704), dim3(256), 0, stream,
                       x, qkv_w, proj_w, xhi, xlo, wqhi, wqlo, wphi, wplo,
                       Qhi, Qlo, Khi, Klo);
    hipLaunchKernelGGL(gemm_qkv, dim3(128, 9), dim3(256), 0, stream,
                       xhi, xlo, wqhi, wqlo, qkv_b,
                       Qhi, Qlo, Khi, Klo, VThi, VTlo);
    hipLaunchKernelGGL(attn_mfma, dim3(64, 8, 4), dim3(256), 0, stream,
                       Qhi, Qlo, Khi, Klo, VThi, VTlo, awshi, awslo);
    hipLaunchKernelGGL(gemm_proj, dim3(256, 3), dim3(128), 0, stream,
                       awshi, awslo, wphi, wplo, proj_b, out);
}